// Round 3
// baseline (2194.705 us; speedup 1.0000x reference)
//
#include <hip/hip_runtime.h>

typedef __bf16 bf16;
typedef __bf16 bf16x8 __attribute__((ext_vector_type(8)));
typedef float  f32x4  __attribute__((ext_vector_type(4)));

#define B_  4
#define L_  2048
#define H_  2048
#define D_  4096
#define N_  16
#define R_  128
#define M_  (B_ * L_)   // 8192 rows

// ---------------- async global->LDS 16B copy ----------------
typedef __attribute__((address_space(1))) const void GV;
typedef __attribute__((address_space(3))) void SV;
__device__ __forceinline__ void async_cp16(const void* g, void* s) {
    __builtin_amdgcn_global_load_lds((GV*)g, (SV*)s, 16, 0, 0);
}

// ---------------- f32 -> bf16 cast (weights) ----------------
__global__ __launch_bounds__(256) void cast_kernel(
    const float* __restrict__ src, bf16* __restrict__ dst)
{
    const size_t i = ((size_t)blockIdx.x * 256 + threadIdx.x) * 8;
    float4 a = *(const float4*)(src + i);
    float4 b = *(const float4*)(src + i + 4);
    bf16x8 o;
    o[0] = (bf16)a.x; o[1] = (bf16)a.y; o[2] = (bf16)a.z; o[3] = (bf16)a.w;
    o[4] = (bf16)b.x; o[5] = (bf16)b.y; o[6] = (bf16)b.z; o[7] = (bf16)b.w;
    *(bf16x8*)(dst + i) = o;
}

// ---------------- fused add + RMSNorm (f32 in; resid f32 out, xnorm bf16 out) ----------------
__global__ __launch_bounds__(256) void add_rmsnorm_kernel(
    const float* __restrict__ hs, const float* __restrict__ res,
    const float* __restrict__ w, float* __restrict__ resid_out,
    bf16* __restrict__ xnorm)
{
    const int m = blockIdx.x;
    const int t = threadIdx.x;
    const size_t base = (size_t)m * H_ + t * 8;
    float4 h0 = *(const float4*)(hs + base);
    float4 h1 = *(const float4*)(hs + base + 4);
    float4 r0 = *(const float4*)(res + base);
    float4 r1 = *(const float4*)(res + base + 4);
    float x[8];
    x[0] = h0.x + r0.x; x[1] = h0.y + r0.y; x[2] = h0.z + r0.z; x[3] = h0.w + r0.w;
    x[4] = h1.x + r1.x; x[5] = h1.y + r1.y; x[6] = h1.z + r1.z; x[7] = h1.w + r1.w;
    float ss = 0.f;
#pragma unroll
    for (int i = 0; i < 8; ++i) ss += x[i] * x[i];
#pragma unroll
    for (int off = 32; off > 0; off >>= 1) ss += __shfl_down(ss, off, 64);
    __shared__ float red[4];
    if ((t & 63) == 0) red[t >> 6] = ss;
    __syncthreads();
    float tot = red[0] + red[1] + red[2] + red[3];
    float rs = rsqrtf(tot * (1.0f / H_) + 1e-5f);
    float4 w0 = *(const float4*)(w + t * 8);
    float4 w1 = *(const float4*)(w + t * 8 + 4);
    float wv[8] = {w0.x, w0.y, w0.z, w0.w, w1.x, w1.y, w1.z, w1.w};
    // residual output is exact f32
    *(float4*)(resid_out + base)     = make_float4(x[0], x[1], x[2], x[3]);
    *(float4*)(resid_out + base + 4) = make_float4(x[4], x[5], x[6], x[7]);
    bf16x8 xo;
#pragma unroll
    for (int i = 0; i < 8; ++i) xo[i] = (bf16)(x[i] * rs * wv[i]);
    *(bf16x8*)(xnorm + base) = xo;
}

// ---------------- generic NT bf16 GEMM, 128x128 tile, mfma 16x16x32 ----------------
// C[m,n] = sum_k A[m,k] * B[n,k]   (A: MxK row-major, B: NxK row-major, both bf16)
// EPI 0: store bf16 C (ldc = N)
// EPI 1: split dbl: col<128 -> bf16 aux_b (ldc 128); 128<=col<160 -> f32 aux_f (ldc 32)
// EPI 2: softplus(acc + bias[col]) -> bf16 C (ldc = N); bias is f32
// EPI 3: store f32 C (ldc = N)   [final out_proj]
// EPI 4: silu(acc) -> bf16 C (ldc = N)   [z branch: pre-applied silu]
template <int EPI>
__global__ __launch_bounds__(256) void gemm_bt(
    const bf16* __restrict__ A, const bf16* __restrict__ Bm,
    int N, int K,
    bf16* __restrict__ Cb, bf16* __restrict__ aux_b, float* __restrict__ aux_f,
    const float* __restrict__ bias)
{
    __shared__ __align__(16) bf16 As[128 * 32];
    __shared__ __align__(16) bf16 Bs[128 * 32];

    const int t  = threadIdx.x;
    const int m0 = blockIdx.y * 128;
    const int n0 = blockIdx.x * 128;

    const int fa = t * 8;        // element index within half-tile (0..2047)
    const int ra = fa >> 5;      // row 0..63
    const int ca = fa & 31;      // col 0..31

    const int wave = t >> 6, lane = t & 63;
    const int wm = (wave >> 1) * 64, wn = (wave & 1) * 64;
    const int lr = lane & 15, quad = lane >> 4;

    int rb0 = n0 + ra;      if (rb0 > N - 1) rb0 = N - 1;
    int rb1 = n0 + 64 + ra; if (rb1 > N - 1) rb1 = N - 1;

    f32x4 acc[4][4] = {};

    for (int k0 = 0; k0 < K; k0 += 32) {
        __syncthreads();
        async_cp16(A  + (size_t)(m0 + ra) * K + k0 + ca,      As + fa);
        async_cp16(A  + (size_t)(m0 + 64 + ra) * K + k0 + ca, As + 2048 + fa);
        async_cp16(Bm + (size_t)rb0 * K + k0 + ca,            Bs + fa);
        async_cp16(Bm + (size_t)rb1 * K + k0 + ca,            Bs + 2048 + fa);
        __syncthreads();

        bf16x8 af[4], bf[4];
#pragma unroll
        for (int i = 0; i < 4; ++i)
            af[i] = *(const bf16x8*)&As[(wm + i * 16 + lr) * 32 + quad * 8];
#pragma unroll
        for (int i = 0; i < 4; ++i)
            bf[i] = *(const bf16x8*)&Bs[(wn + i * 16 + lr) * 32 + quad * 8];
#pragma unroll
        for (int mi = 0; mi < 4; ++mi)
#pragma unroll
            for (int ni = 0; ni < 4; ++ni)
                acc[mi][ni] = __builtin_amdgcn_mfma_f32_16x16x32_bf16(
                    af[mi], bf[ni], acc[mi][ni], 0, 0, 0);
    }

    // epilogue: D[m][n]: n = lane&15, m = quad*4 + r
#pragma unroll
    for (int mi = 0; mi < 4; ++mi) {
#pragma unroll
        for (int ni = 0; ni < 4; ++ni) {
            const int row = m0 + wm + mi * 16 + quad * 4;
            const int col = n0 + wn + ni * 16 + lr;
            if (EPI == 0) {
#pragma unroll
                for (int r = 0; r < 4; ++r)
                    Cb[(size_t)(row + r) * N + col] = (bf16)acc[mi][ni][r];
            } else if (EPI == 1) {
                if (col < 128) {
#pragma unroll
                    for (int r = 0; r < 4; ++r)
                        aux_b[(size_t)(row + r) * 128 + col] = (bf16)acc[mi][ni][r];
                } else if (col < 160) {
#pragma unroll
                    for (int r = 0; r < 4; ++r)
                        aux_f[(size_t)(row + r) * 32 + (col - 128)] = acc[mi][ni][r];
                }
            } else if (EPI == 2) {
                float bv = bias[col];
#pragma unroll
                for (int r = 0; r < 4; ++r) {
                    float v = acc[mi][ni][r] + bv;
                    v = fmaxf(v, 0.f) + log1pf(expf(-fabsf(v)));  // softplus
                    Cb[(size_t)(row + r) * N + col] = (bf16)v;
                }
            } else if (EPI == 3) { // f32 store
#pragma unroll
                for (int r = 0; r < 4; ++r)
                    aux_f[(size_t)(row + r) * N + col] = acc[mi][ni][r];
            } else { // EPI == 4: silu -> bf16
#pragma unroll
                for (int r = 0; r < 4; ++r) {
                    float v = acc[mi][ni][r];
                    v = v * __builtin_amdgcn_rcpf(1.f + __expf(-v));
                    Cb[(size_t)(row + r) * N + col] = (bf16)v;
                }
            }
        }
    }
}

// ---------------- causal depthwise conv (K=4) + silu ----------------
__global__ __launch_bounds__(256) void conv_silu_kernel(
    const bf16* __restrict__ xs, const float* __restrict__ cw,
    const float* __restrict__ cb, bf16* __restrict__ xc)
{
    const size_t idx = (size_t)blockIdx.x * 256 + threadIdx.x;  // < 8192*4096
    const int d = (int)(idx & (D_ - 1));
    const int m = (int)(idx >> 12);
    const int l = m & (L_ - 1);
    float acc = cb[d];
    const float* wp = cw + (size_t)d * 4;
#pragma unroll
    for (int k = 0; k < 4; ++k) {
        int j = l + k - 3;
        if (j >= 0)
            acc += wp[k] * (float)xs[(size_t)(m + k - 3) * D_ + d];
    }
    acc = acc * __builtin_amdgcn_rcpf(1.f + __expf(-acc));   // silu
    xc[idx] = (bf16)acc;
}

// ---------------- selective scan v3 ----------------
// 8 lanes per (b,d) group, 2 states/lane; 2048 waves (2/SIMD, grid-limited).
// Unroll-4 with prefetch distance 4 (ring of statically-indexed register bufs).
// Shuffle reductions batched: 4 independent 3-level xor chains amortize the
// in-order-issue lgkmcnt stall 4x. z arrives pre-silu'd (gemm EPI 4).
// NOTE: dt/y alias (in-place): every dt[m] read is issued >=4 steps before the
// y[m] store, in program order; compiler cannot sink a may-alias load past a store.
__global__ __launch_bounds__(256) void scan_kernel(
    const bf16* dt, const bf16* __restrict__ xc,
    const float* __restrict__ bc, const bf16* __restrict__ sz,
    const float* __restrict__ A_log, const float* __restrict__ Dp,
    bf16* y)
{
    const int t   = threadIdx.x;
    const int grp = blockIdx.x * 32 + (t >> 3);   // global (b,d) group, 0..16383
    const int n2  = (t & 7) * 2;                  // first of this lane's 2 states
    const int b   = grp >> 12;
    const int d   = grp & (D_ - 1);
    const bool w0 = (t & 7) == 0;

    float2 Al = *(const float2*)(A_log + (size_t)d * 16 + n2);
    const float A0 = -__expf(Al.x);
    const float A1 = -__expf(Al.y);
    const float Dpar = Dp[d];

    float h0 = 0.f, h1 = 0.f;

    const size_t bL = (size_t)b * L_ * D_;
    const bf16*  dtb_ = dt + bL;     // uniform bases + 32-bit per-lane offsets
    const bf16*  xcb_ = xc + bL;
    const bf16*  szb_ = sz + bL;
    bf16*        yb_  = y  + bL;
    const float* bcb_ = bc + (size_t)b * L_ * 32 + n2;

    unsigned off  = (unsigned)d;     // element offset into [m][d] tensors
    unsigned boff = 0;               // float offset into bc rows

    // prefetch ring, depth 4 (statically indexed via unroll)
    float  pdt[4], pxc[4], psz[4];
    float2 pB[4], pC[4];
#pragma unroll
    for (int j = 0; j < 4; ++j) {
        pdt[j] = (float)dtb_[off + j * D_];
        pxc[j] = (float)xcb_[off + j * D_];
        psz[j] = (float)szb_[off + j * D_];
        pB[j]  = *(const float2*)(bcb_ + j * 32);
        pC[j]  = *(const float2*)(bcb_ + 16 + j * 32);
    }

    for (int l4 = 0; l4 < L_; l4 += 4) {
        const unsigned offn  = off  + 4u * D_;
        const unsigned boffn = boff + 128u;
        const bool pf = (l4 + 4 < L_);   // wave-uniform guard

        float pv[4], xv[4], sv[4];
#pragma unroll
        for (int j = 0; j < 4; ++j) {
            const float  dta = pdt[j];
            const float  xca = pxc[j];
            const float2 Ba  = pB[j];
            const float2 Ca  = pC[j];
            sv[j] = psz[j];
            xv[j] = xca;
            if (pf) {   // issue next-block loads early (hidden under compute)
                pdt[j] = (float)dtb_[offn + j * D_];
                pxc[j] = (float)xcb_[offn + j * D_];
                psz[j] = (float)szb_[offn + j * D_];
                pB[j]  = *(const float2*)(bcb_ + boffn + j * 32);
                pC[j]  = *(const float2*)(bcb_ + boffn + 16 + j * 32);
            }
            const float dtx = dta * xca;
            const float a0  = __expf(dta * A0);
            const float a1  = __expf(dta * A1);
            h0 = fmaf(a0, h0, dtx * Ba.x);
            h1 = fmaf(a1, h1, dtx * Ba.y);
            pv[j] = fmaf(h1, Ca.y, h0 * Ca.x);
        }
        // 4 independent 3-level xor-reduce chains, interleaved
#pragma unroll
        for (int j = 0; j < 4; ++j) pv[j] += __shfl_xor(pv[j], 1, 64);
#pragma unroll
        for (int j = 0; j < 4; ++j) pv[j] += __shfl_xor(pv[j], 2, 64);
#pragma unroll
        for (int j = 0; j < 4; ++j) pv[j] += __shfl_xor(pv[j], 4, 64);
        if (w0) {
#pragma unroll
            for (int j = 0; j < 4; ++j)
                yb_[off + j * D_] = (bf16)((pv[j] + xv[j] * Dpar) * sv[j]);
        }
        off = offn; boff = boffn;
    }
}

// ---------------- launch ----------------
extern "C" void kernel_launch(void* const* d_in, const int* in_sizes, int n_in,
                              void* d_out, int out_size, void* d_ws, size_t ws_size,
                              hipStream_t stream)
{
    // All reference inputs are float32.
    const float* hs    = (const float*)d_in[0];
    const float* res   = (const float*)d_in[1];
    const float* nw    = (const float*)d_in[2];
    const float* w_in  = (const float*)d_in[3];   // (8192, 2048)
    const float* cw    = (const float*)d_in[4];   // (4096, 1, 4)
    const float* cb    = (const float*)d_in[5];   // (4096,)
    const float* w_xp  = (const float*)d_in[6];   // (160, 4096)
    const float* w_dt  = (const float*)d_in[7];   // (4096, 128)
    const float* b_dt  = (const float*)d_in[8];   // (4096,)
    const float* Alog  = (const float*)d_in[9];   // (4096, 16)
    const float* Dpar  = (const float*)d_in[10];  // (4096,)
    const float* w_out = (const float*)d_in[11];  // (2048, 4096)

    // Outputs are FLOAT32 (reference returns f32): [out (8192x2048), residual (8192x2048)]
    float* out       = (float*)d_out;
    float* resid_out = out + (size_t)M_ * H_;

    char* ws = (char*)d_ws;
    // Compact ws layout — total 206831616 B (197.3 MiB), time-multiplexed:
    bf16*  xsbuf   = (bf16*)(ws);                  // gemm1 xs -> dead after conv
    bf16*  dtbuf   = (bf16*)(ws);                  // alias xsbuf
    bf16*  ybuf    = dtbuf;                        // scan in-place (read-before-write)
    bf16*  zbuf    = (bf16*)(ws + 67108864ull);    // holds silu(z) now
    bf16*  w_out_b = (bf16*)(ws + 67108864ull);    // alias zbuf (dead after scan)
    bf16*  xnorm   = (bf16*)(ws + 134217728ull);
    bf16*  w_in_b  = (bf16*)(ws + 167772160ull);
    bf16*  xconv   = (bf16*)(ws + 134217728ull);   // alias xnorm+w_in_b (dead after gemm1)
    bf16*  dtin    = (bf16*)(ws + 201326592ull);
    float* bcbuf   = (float*)(ws + 203423744ull);
    bf16*  w_xp_b  = (bf16*)(ws + 204472320ull);
    bf16*  w_dt_b  = (bf16*)(ws + 205783040ull);

    // weight casts (f32 -> bf16)
    cast_kernel<<<16777216 / 2048, 256, 0, stream>>>(w_in, w_in_b);
    cast_kernel<<<655360   / 2048, 256, 0, stream>>>(w_xp, w_xp_b);
    cast_kernel<<<524288   / 2048, 256, 0, stream>>>(w_dt, w_dt_b);

    add_rmsnorm_kernel<<<M_, 256, 0, stream>>>(hs, res, nw, resid_out, xnorm);

    // in_proj split: xs = xnorm @ W[:4096]^T (bf16), z branch with fused silu
    gemm_bt<0><<<dim3(32, 64), 256, 0, stream>>>(xnorm, w_in_b, 4096, 2048,
                                                 xsbuf, nullptr, nullptr, nullptr);
    gemm_bt<4><<<dim3(32, 64), 256, 0, stream>>>(xnorm, w_in_b + (size_t)4096 * 2048, 4096, 2048,
                                                 zbuf, nullptr, nullptr, nullptr);

    // conv reads xsbuf, writes xconv (overwrites xnorm + w_in_b, both dead)
    conv_silu_kernel<<<(M_ * D_) / 256, 256, 0, stream>>>(xsbuf, cw, cb, xconv);

    // dbl = xconv @ x_proj_w^T   (N=160, K=4096) -> split dt_in / B,C
    gemm_bt<1><<<dim3(2, 64), 256, 0, stream>>>(xconv, w_xp_b, 160, 4096,
                                                nullptr, dtin, bcbuf, nullptr);

    // dt = softplus(dtin @ dt_proj_w^T + b)  (N=4096, K=128); writes dtbuf (= dead xsbuf)
    gemm_bt<2><<<dim3(32, 64), 256, 0, stream>>>(dtin, w_dt_b, 4096, 128,
                                                 dtbuf, nullptr, nullptr, b_dt);

    // selective scan: 16384 groups * 8 lanes = 512 blocks of 256
    scan_kernel<<<512, 256, 0, stream>>>(dtbuf, xconv, bcbuf, zbuf, Alog, Dpar, ybuf);

    // zbuf dead -> cast out_proj weight into its region
    cast_kernel<<<8388608 / 2048, 256, 0, stream>>>(w_out, w_out_b);

    // out = y @ out_proj_w^T   (N=2048, K=4096) -> f32 store
    gemm_bt<3><<<dim3(16, 64), 256, 0, stream>>>(ybuf, w_out_b, 2048, 4096,
                                                 nullptr, nullptr, out, nullptr);
}

// Round 4
// 1594.042 us; speedup vs baseline: 1.3768x; 1.3768x over previous
//
#include <hip/hip_runtime.h>

typedef __bf16 bf16;
typedef __bf16 bf16x8 __attribute__((ext_vector_type(8)));
typedef float  f32x4  __attribute__((ext_vector_type(4)));

#define B_  4
#define L_  2048
#define H_  2048
#define D_  4096
#define N_  16
#define R_  128
#define M_  (B_ * L_)   // 8192 rows

// ---------------- async global->LDS 16B copy ----------------
typedef __attribute__((address_space(1))) const void GV;
typedef __attribute__((address_space(3))) void SV;
__device__ __forceinline__ void async_cp16(const void* g, void* s) {
    __builtin_amdgcn_global_load_lds((GV*)g, (SV*)s, 16, 0, 0);
}

// ---------------- DPP butterfly add within 8-lane group (no LDS) ----------------
// 0xB1 = quad_perm[1,0,3,2] (xor1), 0x4E = quad_perm[2,3,0,1] (xor2),
// 0x141 = row_half_mirror (pairs quads within 8 lanes). After the three
// levels every lane of the 8-lane group holds the full group sum.
template <int CTRL>
__device__ __forceinline__ float dpp_add(float v) {
    int r = __builtin_amdgcn_update_dpp(0, __builtin_bit_cast(int, v),
                                        CTRL, 0xF, 0xF, true);
    return v + __builtin_bit_cast(float, r);
}

// ---------------- f32 -> bf16 cast (weights) ----------------
__global__ __launch_bounds__(256) void cast_kernel(
    const float* __restrict__ src, bf16* __restrict__ dst)
{
    const size_t i = ((size_t)blockIdx.x * 256 + threadIdx.x) * 8;
    float4 a = *(const float4*)(src + i);
    float4 b = *(const float4*)(src + i + 4);
    bf16x8 o;
    o[0] = (bf16)a.x; o[1] = (bf16)a.y; o[2] = (bf16)a.z; o[3] = (bf16)a.w;
    o[4] = (bf16)b.x; o[5] = (bf16)b.y; o[6] = (bf16)b.z; o[7] = (bf16)b.w;
    *(bf16x8*)(dst + i) = o;
}

// ---------------- fused add + RMSNorm (f32 in; resid f32 out, xnorm bf16 out) ----------------
__global__ __launch_bounds__(256) void add_rmsnorm_kernel(
    const float* __restrict__ hs, const float* __restrict__ res,
    const float* __restrict__ w, float* __restrict__ resid_out,
    bf16* __restrict__ xnorm)
{
    const int m = blockIdx.x;
    const int t = threadIdx.x;
    const size_t base = (size_t)m * H_ + t * 8;
    float4 h0 = *(const float4*)(hs + base);
    float4 h1 = *(const float4*)(hs + base + 4);
    float4 r0 = *(const float4*)(res + base);
    float4 r1 = *(const float4*)(res + base + 4);
    float x[8];
    x[0] = h0.x + r0.x; x[1] = h0.y + r0.y; x[2] = h0.z + r0.z; x[3] = h0.w + r0.w;
    x[4] = h1.x + r1.x; x[5] = h1.y + r1.y; x[6] = h1.z + r1.z; x[7] = h1.w + r1.w;
    float ss = 0.f;
#pragma unroll
    for (int i = 0; i < 8; ++i) ss += x[i] * x[i];
#pragma unroll
    for (int off = 32; off > 0; off >>= 1) ss += __shfl_down(ss, off, 64);
    __shared__ float red[4];
    if ((t & 63) == 0) red[t >> 6] = ss;
    __syncthreads();
    float tot = red[0] + red[1] + red[2] + red[3];
    float rs = rsqrtf(tot * (1.0f / H_) + 1e-5f);
    float4 w0 = *(const float4*)(w + t * 8);
    float4 w1 = *(const float4*)(w + t * 8 + 4);
    float wv[8] = {w0.x, w0.y, w0.z, w0.w, w1.x, w1.y, w1.z, w1.w};
    // residual output is exact f32
    *(float4*)(resid_out + base)     = make_float4(x[0], x[1], x[2], x[3]);
    *(float4*)(resid_out + base + 4) = make_float4(x[4], x[5], x[6], x[7]);
    bf16x8 xo;
#pragma unroll
    for (int i = 0; i < 8; ++i) xo[i] = (bf16)(x[i] * rs * wv[i]);
    *(bf16x8*)(xnorm + base) = xo;
}

// ---------------- generic NT bf16 GEMM, 128x128 tile, mfma 16x16x32 ----------------
// C[m,n] = sum_k A[m,k] * B[n,k]   (A: MxK row-major, B: NxK row-major, both bf16)
// EPI 0: store bf16 C (ldc = N)
// EPI 1: split dbl: col<128 -> bf16 aux_b (ldc 128); 128<=col<160 -> f32 aux_f (ldc 32)
// EPI 2: softplus(acc + bias[col]) -> bf16 C (ldc = N); bias is f32
// EPI 3: store f32 C (ldc = N)   [final out_proj]
// EPI 4: silu(acc) -> bf16 C (ldc = N)   [z branch: pre-applied silu]
template <int EPI>
__global__ __launch_bounds__(256) void gemm_bt(
    const bf16* __restrict__ A, const bf16* __restrict__ Bm,
    int N, int K,
    bf16* __restrict__ Cb, bf16* __restrict__ aux_b, float* __restrict__ aux_f,
    const float* __restrict__ bias)
{
    __shared__ __align__(16) bf16 As[128 * 32];
    __shared__ __align__(16) bf16 Bs[128 * 32];

    const int t  = threadIdx.x;
    const int m0 = blockIdx.y * 128;
    const int n0 = blockIdx.x * 128;

    const int fa = t * 8;        // element index within half-tile (0..2047)
    const int ra = fa >> 5;      // row 0..63
    const int ca = fa & 31;      // col 0..31

    const int wave = t >> 6, lane = t & 63;
    const int wm = (wave >> 1) * 64, wn = (wave & 1) * 64;
    const int lr = lane & 15, quad = lane >> 4;

    int rb0 = n0 + ra;      if (rb0 > N - 1) rb0 = N - 1;
    int rb1 = n0 + 64 + ra; if (rb1 > N - 1) rb1 = N - 1;

    f32x4 acc[4][4] = {};

    for (int k0 = 0; k0 < K; k0 += 32) {
        __syncthreads();
        async_cp16(A  + (size_t)(m0 + ra) * K + k0 + ca,      As + fa);
        async_cp16(A  + (size_t)(m0 + 64 + ra) * K + k0 + ca, As + 2048 + fa);
        async_cp16(Bm + (size_t)rb0 * K + k0 + ca,            Bs + fa);
        async_cp16(Bm + (size_t)rb1 * K + k0 + ca,            Bs + 2048 + fa);
        __syncthreads();

        bf16x8 af[4], bf[4];
#pragma unroll
        for (int i = 0; i < 4; ++i)
            af[i] = *(const bf16x8*)&As[(wm + i * 16 + lr) * 32 + quad * 8];
#pragma unroll
        for (int i = 0; i < 4; ++i)
            bf[i] = *(const bf16x8*)&Bs[(wn + i * 16 + lr) * 32 + quad * 8];
#pragma unroll
        for (int mi = 0; mi < 4; ++mi)
#pragma unroll
            for (int ni = 0; ni < 4; ++ni)
                acc[mi][ni] = __builtin_amdgcn_mfma_f32_16x16x32_bf16(
                    af[mi], bf[ni], acc[mi][ni], 0, 0, 0);
    }

    // epilogue: D[m][n]: n = lane&15, m = quad*4 + r
#pragma unroll
    for (int mi = 0; mi < 4; ++mi) {
#pragma unroll
        for (int ni = 0; ni < 4; ++ni) {
            const int row = m0 + wm + mi * 16 + quad * 4;
            const int col = n0 + wn + ni * 16 + lr;
            if (EPI == 0) {
#pragma unroll
                for (int r = 0; r < 4; ++r)
                    Cb[(size_t)(row + r) * N + col] = (bf16)acc[mi][ni][r];
            } else if (EPI == 1) {
                if (col < 128) {
#pragma unroll
                    for (int r = 0; r < 4; ++r)
                        aux_b[(size_t)(row + r) * 128 + col] = (bf16)acc[mi][ni][r];
                } else if (col < 160) {
#pragma unroll
                    for (int r = 0; r < 4; ++r)
                        aux_f[(size_t)(row + r) * 32 + (col - 128)] = acc[mi][ni][r];
                }
            } else if (EPI == 2) {
                float bv = bias[col];
#pragma unroll
                for (int r = 0; r < 4; ++r) {
                    float v = acc[mi][ni][r] + bv;
                    v = fmaxf(v, 0.f) + log1pf(expf(-fabsf(v)));  // softplus
                    Cb[(size_t)(row + r) * N + col] = (bf16)v;
                }
            } else if (EPI == 3) { // f32 store
#pragma unroll
                for (int r = 0; r < 4; ++r)
                    aux_f[(size_t)(row + r) * N + col] = acc[mi][ni][r];
            } else { // EPI == 4: silu -> bf16
#pragma unroll
                for (int r = 0; r < 4; ++r) {
                    float v = acc[mi][ni][r];
                    v = v * __builtin_amdgcn_rcpf(1.f + __expf(-v));
                    Cb[(size_t)(row + r) * N + col] = (bf16)v;
                }
            }
        }
    }
}

// ---------------- causal depthwise conv (K=4) + silu ----------------
__global__ __launch_bounds__(256) void conv_silu_kernel(
    const bf16* __restrict__ xs, const float* __restrict__ cw,
    const float* __restrict__ cb, bf16* __restrict__ xc)
{
    const size_t idx = (size_t)blockIdx.x * 256 + threadIdx.x;  // < 8192*4096
    const int d = (int)(idx & (D_ - 1));
    const int m = (int)(idx >> 12);
    const int l = m & (L_ - 1);
    float acc = cb[d];
    const float* wp = cw + (size_t)d * 4;
#pragma unroll
    for (int k = 0; k < 4; ++k) {
        int j = l + k - 3;
        if (j >= 0)
            acc += wp[k] * (float)xs[(size_t)(m + k - 3) * D_ + d];
    }
    acc = acc * __builtin_amdgcn_rcpf(1.f + __expf(-acc));   // silu
    xc[idx] = (bf16)acc;
}

// ---------------- selective scan v4 ----------------
// 8 lanes per (b,d) group, 2 states/lane; 2048 waves (2/SIMD, grid-limited).
// ALL pointers genuinely disjoint now (y has its own buffer) -> full restrict,
// stores never force a waitcnt drain of prefetch loads.
// Prefetch ring depth 8 (distance 8 steps), statically indexed (registers).
// Group reduction via 3 DPP VALU adds (no LDS, no lgkmcnt).
__global__ __launch_bounds__(256) void scan_kernel(
    const bf16* __restrict__ dt, const bf16* __restrict__ xc,
    const float* __restrict__ bc, const bf16* __restrict__ sz,
    const float* __restrict__ A_log, const float* __restrict__ Dp,
    bf16* __restrict__ y)
{
    const int t   = threadIdx.x;
    const int grp = blockIdx.x * 32 + (t >> 3);   // global (b,d) group, 0..16383
    const int n2  = (t & 7) * 2;                  // first of this lane's 2 states
    const int b   = grp >> 12;
    const int d   = grp & (D_ - 1);
    const bool w0 = (t & 7) == 0;

    float2 Al = *(const float2*)(A_log + (size_t)d * 16 + n2);
    const float A0 = -__expf(Al.x);
    const float A1 = -__expf(Al.y);
    const float Dpar = Dp[d];

    float h0 = 0.f, h1 = 0.f;

    const size_t bL = (size_t)b * L_ * D_;
    const bf16*  dtp = dt + bL + d;
    const bf16*  xcp = xc + bL + d;
    const bf16*  szp = sz + bL + d;
    bf16*        yp  = y  + bL + d;
    const float* bcp = bc + (size_t)b * (L_ * 32) + n2;

    unsigned off  = 0;   // element offset (row l) * D_
    unsigned boff = 0;   // float offset into bc rows (row l * 32)

    // prefetch ring, depth 8 (statically indexed -> registers)
    float  rdt[8], rxc[8], rsz[8];
    float2 rB[8], rC[8];
#pragma unroll
    for (int j = 0; j < 8; ++j) {
        rdt[j] = (float)dtp[j * D_];
        rxc[j] = (float)xcp[j * D_];
        rsz[j] = (float)szp[j * D_];
        rB[j]  = *(const float2*)(bcp + j * 32);
        rC[j]  = *(const float2*)(bcp + 16 + j * 32);
    }

#define SBLOCK(PF)                                                            \
    {                                                                         \
        float pv[8], xvv[8], svv[8];                                          \
        _Pragma("unroll")                                                     \
        for (int j = 0; j < 8; ++j) {                                         \
            const float  dta = rdt[j];                                        \
            const float  xca = rxc[j];                                        \
            const float2 Ba  = rB[j];                                         \
            const float2 Ca  = rC[j];                                         \
            svv[j] = rsz[j];                                                  \
            xvv[j] = xca;                                                     \
            if (PF) {                                                         \
                rdt[j] = (float)dtp[off + (8 + j) * D_];                      \
                rxc[j] = (float)xcp[off + (8 + j) * D_];                      \
                rsz[j] = (float)szp[off + (8 + j) * D_];                      \
                rB[j]  = *(const float2*)(bcp + boff + (8 + j) * 32);         \
                rC[j]  = *(const float2*)(bcp + boff + 16 + (8 + j) * 32);    \
            }                                                                 \
            const float dtx = dta * xca;                                      \
            h0 = fmaf(__expf(dta * A0), h0, dtx * Ba.x);                      \
            h1 = fmaf(__expf(dta * A1), h1, dtx * Ba.y);                      \
            pv[j] = fmaf(h1, Ca.y, h0 * Ca.x);                                \
        }                                                                     \
        _Pragma("unroll")                                                     \
        for (int j = 0; j < 8; ++j) {                                         \
            pv[j] = dpp_add<0xB1>(pv[j]);                                     \
            pv[j] = dpp_add<0x4E>(pv[j]);                                     \
            pv[j] = dpp_add<0x141>(pv[j]);                                    \
        }                                                                     \
        if (w0) {                                                             \
            _Pragma("unroll")                                                 \
            for (int j = 0; j < 8; ++j)                                       \
                yp[off + j * D_] = (bf16)((pv[j] + xvv[j] * Dpar) * svv[j]);  \
        }                                                                     \
    }

    for (int l8 = 0; l8 < L_ - 8; l8 += 8) {
        SBLOCK(1);
        off  += 8u * D_;
        boff += 8u * 32u;
    }
    SBLOCK(0);   // last 8 steps: no prefetch
#undef SBLOCK
}

// ---------------- launch ----------------
extern "C" void kernel_launch(void* const* d_in, const int* in_sizes, int n_in,
                              void* d_out, int out_size, void* d_ws, size_t ws_size,
                              hipStream_t stream)
{
    // All reference inputs are float32.
    const float* hs    = (const float*)d_in[0];
    const float* res   = (const float*)d_in[1];
    const float* nw    = (const float*)d_in[2];
    const float* w_in  = (const float*)d_in[3];   // (8192, 2048)
    const float* cw    = (const float*)d_in[4];   // (4096, 1, 4)
    const float* cb    = (const float*)d_in[5];   // (4096,)
    const float* w_xp  = (const float*)d_in[6];   // (160, 4096)
    const float* w_dt  = (const float*)d_in[7];   // (4096, 128)
    const float* b_dt  = (const float*)d_in[8];   // (4096,)
    const float* Alog  = (const float*)d_in[9];   // (4096, 16)
    const float* Dpar  = (const float*)d_in[10];  // (4096,)
    const float* w_out = (const float*)d_in[11];  // (2048, 4096)

    // Outputs are FLOAT32: [out (8192x2048), residual (8192x2048)]
    float* out       = (float*)d_out;
    float* resid_out = out + (size_t)M_ * H_;

    // d_out's first 64 MiB (`out`) is written only by the FINAL GEMM ->
    // use it as scratch for xs then dt (exactly 8192*4096 bf16 = 64 MiB).
    bf16* dscr = (bf16*)d_out;     // xs, then dt (xs dead after conv)

    char* ws = (char*)d_ws;
    // ws layout (197.3 MiB, time-multiplexed):
    bf16*  ybuf    = (bf16*)(ws);                  // y: OWN region (no alias with dt!)
    bf16*  zbuf    = (bf16*)(ws + 67108864ull);    // silu(z)
    bf16*  w_out_b = (bf16*)(ws + 67108864ull);    // alias zbuf (dead after scan)
    bf16*  xnorm   = (bf16*)(ws + 134217728ull);
    bf16*  w_in_b  = (bf16*)(ws + 167772160ull);
    bf16*  xconv   = (bf16*)(ws + 134217728ull);   // alias xnorm+w_in_b (dead after gemm1)
    bf16*  dtin    = (bf16*)(ws + 201326592ull);
    float* bcbuf   = (float*)(ws + 203423744ull);
    bf16*  w_xp_b  = (bf16*)(ws + 204472320ull);
    bf16*  w_dt_b  = (bf16*)(ws + 205783040ull);

    // weight casts (f32 -> bf16)
    cast_kernel<<<16777216 / 2048, 256, 0, stream>>>(w_in, w_in_b);
    cast_kernel<<<655360   / 2048, 256, 0, stream>>>(w_xp, w_xp_b);
    cast_kernel<<<524288   / 2048, 256, 0, stream>>>(w_dt, w_dt_b);

    add_rmsnorm_kernel<<<M_, 256, 0, stream>>>(hs, res, nw, resid_out, xnorm);

    // in_proj split: xs -> d_out scratch (bf16), z branch with fused silu -> ws
    gemm_bt<0><<<dim3(32, 64), 256, 0, stream>>>(xnorm, w_in_b, 4096, 2048,
                                                 dscr, nullptr, nullptr, nullptr);
    gemm_bt<4><<<dim3(32, 64), 256, 0, stream>>>(xnorm, w_in_b + (size_t)4096 * 2048, 4096, 2048,
                                                 zbuf, nullptr, nullptr, nullptr);

    // conv reads xs (d_out scratch), writes xconv (overwrites xnorm + w_in_b, both dead)
    conv_silu_kernel<<<(M_ * D_) / 256, 256, 0, stream>>>(dscr, cw, cb, xconv);

    // dbl = xconv @ x_proj_w^T   (N=160, K=4096) -> split dt_in / B,C
    gemm_bt<1><<<dim3(2, 64), 256, 0, stream>>>(xconv, w_xp_b, 160, 4096,
                                                nullptr, dtin, bcbuf, nullptr);

    // dt = softplus(dtin @ dt_proj_w^T + b)  (N=4096, K=128) -> d_out scratch (xs dead)
    gemm_bt<2><<<dim3(32, 64), 256, 0, stream>>>(dtin, w_dt_b, 4096, 128,
                                                 dscr, nullptr, nullptr, b_dt);

    // selective scan: reads dt (d_out scratch), writes y -> ws+0 (disjoint!)
    scan_kernel<<<512, 256, 0, stream>>>(dscr, xconv, bcbuf, zbuf, Alog, Dpar, ybuf);

    // zbuf dead -> cast out_proj weight into its region
    cast_kernel<<<8388608 / 2048, 256, 0, stream>>>(w_out, w_out_b);

    // out = y @ out_proj_w^T (N=2048, K=4096): reads ws only, writes d_out (dt dead)
    gemm_bt<3><<<dim3(16, 64), 256, 0, stream>>>(ybuf, w_out_b, 2048, 4096,
                                                 nullptr, nullptr, out, nullptr);
}